// Round 1
// baseline (138.848 us; speedup 1.0000x reference)
//
#include <hip/hip_runtime.h>
#include <cstddef>

#define NB 64
#define NP 8732
#define NM 16
#define NC 21
#define S_SPLIT 8

// CLASS_W: base 1.0; [3,4,5,9,10,11,16,17,18]=2.5; [15,7,12,8]=0.75; [0]=0.5
__constant__ float c_w[NC] = {
    0.5f, 1.0f, 1.0f, 2.5f, 2.5f, 2.5f, 1.0f, 0.75f, 0.75f, 2.5f, 2.5f,
    2.5f, 0.75f, 1.0f, 1.0f, 0.75f, 2.5f, 2.5f, 2.5f, 1.0f, 1.0f};

// ---------------- Kernel 1: matching (one block per batch) ----------------
__global__ __launch_bounds__(256) void k_match(
    const float4* __restrict__ defaults, const float4* __restrict__ gtb,
    int* __restrict__ bti, float* __restrict__ bto)
{
    const int b = blockIdx.x, t = threadIdx.x;
    __shared__ float s_t0[NM], s_t1[NM], s_t2[NM], s_t3[NM], s_area[NM];
    __shared__ float s_bpv[NM][256];
    __shared__ int   s_bpi[NM][256];

    if (t < NM) {
        float4 g = gtb[b * NM + t];
        s_t0[t] = g.x; s_t1[t] = g.y; s_t2[t] = g.z; s_t3[t] = g.w;
        s_area[t] = (g.z - g.x) * (g.w - g.y);
    }
    __syncthreads();

    float bpv[NM]; int bpi[NM];
    #pragma unroll
    for (int j = 0; j < NM; j++) { bpv[j] = -1.0f; bpi[j] = 0; }

    for (int p = t; p < NP; p += 256) {
        float4 d = defaults[p];
        float a1 = (d.z - d.x) * (d.w - d.y);
        float bv = -1.0f; int bj = 0;
        #pragma unroll
        for (int j = 0; j < NM; j++) {
            float w = fminf(d.z, s_t2[j]) - fmaxf(d.x, s_t0[j]);
            float h = fminf(d.w, s_t3[j]) - fmaxf(d.y, s_t1[j]);
            w = fmaxf(w, 0.0f); h = fmaxf(h, 0.0f);
            float inter = w * h;
            float iou = inter / (a1 + s_area[j] - inter);
            if (iou > bv)     { bv = iou; bj = j; }       // first-occurrence over j
            if (iou > bpv[j]) { bpv[j] = iou; bpi[j] = p; } // first-occurrence over p (ascending visit)
        }
        bto[b * NP + p] = bv;
        bti[b * NP + p] = bj;
    }

    #pragma unroll
    for (int j = 0; j < NM; j++) { s_bpv[j][t] = bpv[j]; s_bpi[j][t] = bpi[j]; }
    __syncthreads();
    for (int off = 128; off > 0; off >>= 1) {
        if (t < off) {
            #pragma unroll
            for (int j = 0; j < NM; j++) {
                float v1 = s_bpv[j][t], v2 = s_bpv[j][t + off];
                int   i1 = s_bpi[j][t], i2 = s_bpi[j][t + off];
                if (v2 > v1 || (v2 == v1 && i2 < i1)) { s_bpv[j][t] = v2; s_bpi[j][t] = i2; }
            }
        }
        __syncthreads();
    }
    if (t == 0) {
        // sequential override loop (later j wins) — exact ref semantics
        for (int j = 0; j < NM; j++) {
            int p = s_bpi[j][0];
            bti[b * NP + p] = j;
            bto[b * NP + p] = 2.0f;
        }
    }
}

// ---------------- Kernel 2: per-prior losses + partial sums ----------------
__global__ __launch_bounds__(256) void k_loss(
    const float4* __restrict__ loc, const float* __restrict__ conf,
    const float* __restrict__ cent, const float4* __restrict__ defaults,
    const float4* __restrict__ gtb, const int* __restrict__ gtl,
    const int* __restrict__ bti, const float* __restrict__ bto,
    float* __restrict__ lossc,
    int* __restrict__ nposP, float* __restrict__ locP,
    float* __restrict__ centP, float* __restrict__ pfocP)
{
    const int b = blockIdx.x, s = blockIdx.y, t = threadIdx.x;
    __shared__ float s_t0[NM], s_t1[NM], s_t2[NM], s_t3[NM];
    __shared__ int s_lab[NM];
    if (t < NM) {
        float4 g = gtb[b * NM + t];
        s_t0[t] = g.x; s_t1[t] = g.y; s_t2[t] = g.z; s_t3[t] = g.w;
        s_lab[t] = gtl[b * NM + t];
    }
    __syncthreads();

    float locS = 0.0f, centS = 0.0f, pfocS = 0.0f; int np = 0;

    for (int p = s * 256 + t; p < NP; p += 256 * S_SPLIT) {
        int   j  = bti[b * NP + p];
        float ov = bto[b * NP + p];
        int lab = (ov < 0.5f) ? 0 : s_lab[j];
        bool pos = lab > 0;

        // focal loss on conf_preds[b,p,:]
        const float* cp = conf + ((size_t)(b * NP) + p) * NC;
        float m = cp[0];
        #pragma unroll
        for (int c = 1; c < NC; c++) m = fmaxf(m, cp[c]);
        float se = 0.0f;
        #pragma unroll
        for (int c = 0; c < NC; c++) se += expf(cp[c] - m);
        float logpt = cp[lab] - m - logf(se);
        float ce = -logpt;
        float pt = expf(logpt);
        float omp = 1.0f - pt;
        float focal = 0.25f * omp * omp * c_w[lab] * ce;

        lossc[b * NP + p] = pos ? 0.0f : focal;

        if (pos) {
            float g0 = s_t0[j], g1 = s_t1[j], g2 = s_t2[j], g3 = s_t3[j];
            float4 d = defaults[p];
            float dw = d.z - d.x, dh = d.w - d.y;
            float gw = g2 - g0,  gh = g3 - g1;
            float dcx = d.x + dw * 0.5f, dcy = d.y + dh * 0.5f;
            float gcx = g0 + gw * 0.5f,  gcy = g1 + gh * 0.5f;
            float e0 = (gcx - dcx) / (dw * 0.1f + 1e-8f);
            float e1 = (gcy - dcy) / (dh * 0.1f + 1e-8f);
            float e2 = logf(gw / (dw + 1e-8f) + 1e-8f) / 0.1f;
            float e3 = logf(gh / (dh + 1e-8f) + 1e-8f) / 0.1f;
            float4 lp = loc[(size_t)b * NP + p];
            float a, sl = 0.0f;
            a = fabsf(lp.x - e0); sl += (a < 1.0f) ? 0.5f * a * a : a - 0.5f;
            a = fabsf(lp.y - e1); sl += (a < 1.0f) ? 0.5f * a * a : a - 0.5f;
            a = fabsf(lp.z - e2); sl += (a < 1.0f) ? 0.5f * a * a : a - 0.5f;
            a = fabsf(lp.w - e3); sl += (a < 1.0f) ? 0.5f * a * a : a - 0.5f;
            locS += sl;

            // centerness target (ref: cx=(l+r)/2)
            float ccx = (g0 + g2) * 0.5f, ccy = (g1 + g3) * 0.5f;
            float ld = ccx - g0, rd = g2 - ccx, td = ccy - g1, bd = g3 - ccy;
            float centT = sqrtf((fminf(ld, rd) / fmaxf(ld, rd + 1e-8f)) *
                                (fminf(td, bd) / fmaxf(td, bd + 1e-8f)));
            float x = cent[(size_t)b * NP + p];
            float bce = fmaxf(x, 0.0f) - x * centT + log1pf(expf(-fabsf(x)));
            centS += bce;
            pfocS += focal;
            np++;
        }
    }

    __shared__ float r0[256], r1[256], r2[256];
    __shared__ int r3[256];
    r0[t] = locS; r1[t] = centS; r2[t] = pfocS; r3[t] = np;
    __syncthreads();
    for (int off = 128; off > 0; off >>= 1) {
        if (t < off) {
            r0[t] += r0[t + off]; r1[t] += r1[t + off];
            r2[t] += r2[t + off]; r3[t] += r3[t + off];
        }
        __syncthreads();
    }
    if (t == 0) {
        int idx = b * S_SPLIT + s;
        locP[idx] = r0[0]; centP[idx] = r1[0]; pfocP[idx] = r2[0]; nposP[idx] = r3[0];
    }
}

// ---------------- Kernel 3: per-batch top-k of loss_c (radix/bit select) ----------------
__global__ __launch_bounds__(256) void k_topk(
    const float* __restrict__ lossc, const int* __restrict__ nposP,
    float* __restrict__ topkP, float* __restrict__ selcP)
{
    const int b = blockIdx.x, t = threadIdx.x;
    __shared__ unsigned s_key[NP];
    __shared__ int s_ri[256];
    __shared__ float s_rf[256];

    for (int p = t; p < NP; p += 256)
        s_key[p] = __float_as_uint(lossc[b * NP + p]);   // loss_c >= 0 -> bits order-isomorphic

    int np = 0;
    for (int s = 0; s < S_SPLIT; s++) np += nposP[b * S_SPLIT + s];
    int k = min(3 * np, NP - 1);
    __syncthreads();

    unsigned vk = 0;  // k-th largest key value
    if (k > 0) {
        for (int bit = 31; bit >= 0; --bit) {
            unsigned trial = vk | (1u << bit);
            int cnt = 0;
            for (int p = t; p < NP; p += 256) cnt += (s_key[p] >= trial) ? 1 : 0;
            s_ri[t] = cnt; __syncthreads();
            for (int off = 128; off > 0; off >>= 1) {
                if (t < off) s_ri[t] += s_ri[t + off];
                __syncthreads();
            }
            int total = s_ri[0];
            __syncthreads();           // protect s_ri[0] before next iteration's writes
            if (total >= k) vk = trial;
        }
    }

    int cgt = 0; float sgt = 0.0f;
    for (int p = t; p < NP; p += 256) {
        unsigned kk = s_key[p];
        if (kk > vk) { cgt++; sgt += __uint_as_float(kk); }
    }
    s_ri[t] = cgt; s_rf[t] = sgt; __syncthreads();
    for (int off = 128; off > 0; off >>= 1) {
        if (t < off) { s_ri[t] += s_ri[t + off]; s_rf[t] += s_rf[t + off]; }
        __syncthreads();
    }
    if (t == 0) {
        float topk = (k > 0)
            ? (s_rf[0] + (float)(k - s_ri[0]) * __uint_as_float(vk))
            : 0.0f;
        topkP[b] = topk;
        selcP[b] = (float)(np + k);   // vk>0 in practice -> pos/neg disjoint
    }
}

// ---------------- Kernel 4: final deterministic combine ----------------
__global__ void k_final(const int* __restrict__ nposP, const float* __restrict__ locP,
                        const float* __restrict__ centP, const float* __restrict__ pfocP,
                        const float* __restrict__ topkP, const float* __restrict__ selcP,
                        float* __restrict__ out)
{
    if (threadIdx.x == 0 && blockIdx.x == 0) {
        int np = 0; float l = 0.0f, c = 0.0f, pf = 0.0f;
        for (int i = 0; i < NB * S_SPLIT; i++) {
            np += nposP[i]; l += locP[i]; c += centP[i]; pf += pfocP[i];
        }
        float tk = 0.0f, sc = 0.0f;
        for (int b = 0; b < NB; b++) { tk += topkP[b]; sc += selcP[b]; }
        float fnp = (float)np;
        float loss = 2.0f * (l / fnp) + (pf + tk) / sc + (c / fnp);
        out[0] = loss;
    }
}

extern "C" void kernel_launch(void* const* d_in, const int* in_sizes, int n_in,
                              void* d_out, int out_size, void* d_ws, size_t ws_size,
                              hipStream_t stream) {
    const float4* loc      = (const float4*)d_in[0];
    const float*  conf     = (const float*)d_in[1];
    const float*  cent     = (const float*)d_in[2];
    const float4* defaults = (const float4*)d_in[3];
    const float4* gtb      = (const float4*)d_in[4];
    const int*    gtl      = (const int*)d_in[5];
    float* out = (float*)d_out;

    const size_t BP = (size_t)NB * NP;
    char* w = (char*)d_ws;
    int*   bti   = (int*)w;                        // BP ints
    float* bto   = (float*)(w + BP * 4);           // BP floats
    float* lossc = (float*)(w + 2 * BP * 4);       // BP floats
    char* w2 = w + 3 * BP * 4;
    int*   nposP = (int*)w2;                       // NB*S_SPLIT
    float* locP  = (float*)(w2 + NB * S_SPLIT * 4);
    float* centP = (float*)(w2 + 2 * NB * S_SPLIT * 4);
    float* pfocP = (float*)(w2 + 3 * NB * S_SPLIT * 4);
    float* topkP = (float*)(w2 + 4 * NB * S_SPLIT * 4);
    float* selcP = (float*)(w2 + 4 * NB * S_SPLIT * 4 + NB * 4);

    k_match<<<NB, 256, 0, stream>>>(defaults, gtb, bti, bto);
    k_loss<<<dim3(NB, S_SPLIT), 256, 0, stream>>>(loc, conf, cent, defaults, gtb, gtl,
                                                  bti, bto, lossc, nposP, locP, centP, pfocP);
    k_topk<<<NB, 256, 0, stream>>>(lossc, nposP, topkP, selcP);
    k_final<<<1, 64, 0, stream>>>(nposP, locP, centP, pfocP, topkP, selcP, out);
}

// Round 2
// 75.590 us; speedup vs baseline: 1.8369x; 1.8369x over previous
//
#include <hip/hip_runtime.h>
#include <cstddef>

#define NB 64
#define NP 8732
#define NM 16
#define NC 21
#define S_SPLIT 16
#define PSPLIT 16
#define CH 546      // ceil(NP/PSPLIT)
#define NK 35       // ceil(NP/256)

// CLASS_W: base 1.0; [3,4,5,9,10,11,16,17,18]=2.5; [15,7,12,8]=0.75; [0]=0.5
__constant__ float c_w[NC] = {
    0.5f, 1.0f, 1.0f, 2.5f, 2.5f, 2.5f, 1.0f, 0.75f, 0.75f, 2.5f, 2.5f,
    2.5f, 0.75f, 1.0f, 1.0f, 0.75f, 2.5f, 2.5f, 2.5f, 1.0f, 1.0f};

// ------------- Kernel 1a: matching, split over (batch, prior-chunk) -------------
__global__ __launch_bounds__(256) void k_match_part(
    const float4* __restrict__ defaults, const float4* __restrict__ gtb,
    int* __restrict__ bti, float* __restrict__ bto,
    float* __restrict__ pbv, int* __restrict__ pbi)
{
    const int b = blockIdx.x, s = blockIdx.y, t = threadIdx.x;
    __shared__ float s_t0[NM], s_t1[NM], s_t2[NM], s_t3[NM], s_area[NM];
    __shared__ float s_wv[NM][4];
    __shared__ int   s_wi[NM][4];

    if (t < NM) {
        float4 g = gtb[b * NM + t];
        s_t0[t] = g.x; s_t1[t] = g.y; s_t2[t] = g.z; s_t3[t] = g.w;
        s_area[t] = (g.z - g.x) * (g.w - g.y);
    }
    __syncthreads();

    float bpv[NM]; int bpi[NM];
    #pragma unroll
    for (int j = 0; j < NM; j++) { bpv[j] = -1.0f; bpi[j] = 0x7fffffff; }

    const int pend = min(NP, (s + 1) * CH);
    for (int p = s * CH + t; p < pend; p += 256) {
        float4 d = defaults[p];
        float a1 = (d.z - d.x) * (d.w - d.y);
        float bv = -1.0f; int bj = 0;
        #pragma unroll
        for (int j = 0; j < NM; j++) {
            float w = fminf(d.z, s_t2[j]) - fmaxf(d.x, s_t0[j]);
            float h = fminf(d.w, s_t3[j]) - fmaxf(d.y, s_t1[j]);
            w = fmaxf(w, 0.0f); h = fmaxf(h, 0.0f);
            float inter = w * h;
            float iou = inter / (a1 + s_area[j] - inter);
            if (iou > bv)     { bv = iou; bj = j; }        // first-occurrence over j
            if (iou > bpv[j]) { bpv[j] = iou; bpi[j] = p; } // smallest p kept (ascending visit)
        }
        bto[b * NP + p] = bv;
        bti[b * NP + p] = bj;
    }

    // per-truth partial argmax: wave shfl butterfly, then cross-wave via tiny LDS
    const int lane = t & 63, wv = t >> 6;
    #pragma unroll
    for (int j = 0; j < NM; j++) {
        float v = bpv[j]; int i = bpi[j];
        #pragma unroll
        for (int off = 32; off > 0; off >>= 1) {
            float v2 = __shfl_down(v, off);
            int   i2 = __shfl_down(i, off);
            if (v2 > v || (v2 == v && i2 < i)) { v = v2; i = i2; }
        }
        if (lane == 0) { s_wv[j][wv] = v; s_wi[j][wv] = i; }
    }
    __syncthreads();
    if (t < NM) {
        float v = s_wv[t][0]; int i = s_wi[t][0];
        #pragma unroll
        for (int w = 1; w < 4; w++) {
            float v2 = s_wv[t][w]; int i2 = s_wi[t][w];
            if (v2 > v || (v2 == v && i2 < i)) { v = v2; i = i2; }
        }
        pbv[(b * PSPLIT + s) * NM + t] = v;
        pbi[(b * PSPLIT + s) * NM + t] = i;
    }
}

// ------------- Kernel 1b: combine per-truth argmax + sequential overrides -------------
__global__ void k_match_fix(const float* __restrict__ pbv, const int* __restrict__ pbi,
                            int* __restrict__ bti, float* __restrict__ bto)
{
    const int b = blockIdx.x, t = threadIdx.x;
    __shared__ int s_pi[NM];
    if (t < NM) {
        float v = -2.0f; int i = 0x7fffffff;
        for (int s = 0; s < PSPLIT; s++) {
            float v2 = pbv[(b * PSPLIT + s) * NM + t];
            int   i2 = pbi[(b * PSPLIT + s) * NM + t];
            if (v2 > v || (v2 == v && i2 < i)) { v = v2; i = i2; }
        }
        s_pi[t] = i;
    }
    __syncthreads();
    if (t == 0) {
        // sequential override loop (later j wins) — exact ref semantics
        for (int j = 0; j < NM; j++) {
            int p = s_pi[j];
            bti[b * NP + p] = j;
            bto[b * NP + p] = 2.0f;
        }
    }
}

// ---------------- Kernel 2: per-prior losses + partial sums ----------------
__global__ __launch_bounds__(256) void k_loss(
    const float4* __restrict__ loc, const float* __restrict__ conf,
    const float* __restrict__ cent, const float4* __restrict__ defaults,
    const float4* __restrict__ gtb, const int* __restrict__ gtl,
    const int* __restrict__ bti, const float* __restrict__ bto,
    float* __restrict__ lossc,
    int* __restrict__ nposP, float* __restrict__ locP,
    float* __restrict__ centP, float* __restrict__ pfocP)
{
    const int b = blockIdx.x, s = blockIdx.y, t = threadIdx.x;
    __shared__ float s_t0[NM], s_t1[NM], s_t2[NM], s_t3[NM];
    __shared__ int s_lab[NM];
    if (t < NM) {
        float4 g = gtb[b * NM + t];
        s_t0[t] = g.x; s_t1[t] = g.y; s_t2[t] = g.z; s_t3[t] = g.w;
        s_lab[t] = gtl[b * NM + t];
    }
    __syncthreads();

    float locS = 0.0f, centS = 0.0f, pfocS = 0.0f; int np = 0;

    for (int p = s * 256 + t; p < NP; p += 256 * S_SPLIT) {
        int   j  = bti[b * NP + p];
        float ov = bto[b * NP + p];
        int lab = (ov < 0.5f) ? 0 : s_lab[j];
        bool pos = lab > 0;

        const float* cp = conf + ((size_t)(b * NP) + p) * NC;
        float m = cp[0];
        #pragma unroll
        for (int c = 1; c < NC; c++) m = fmaxf(m, cp[c]);
        float se = 0.0f;
        #pragma unroll
        for (int c = 0; c < NC; c++) se += __expf(cp[c] - m);
        float logpt = cp[lab] - m - __logf(se);
        float ce = -logpt;
        float pt = __expf(logpt);
        float omp = 1.0f - pt;
        float focal = 0.25f * omp * omp * c_w[lab] * ce;

        lossc[b * NP + p] = pos ? 0.0f : focal;

        if (pos) {
            float g0 = s_t0[j], g1 = s_t1[j], g2 = s_t2[j], g3 = s_t3[j];
            float4 d = defaults[p];
            float dw = d.z - d.x, dh = d.w - d.y;
            float gw = g2 - g0,  gh = g3 - g1;
            float dcx = d.x + dw * 0.5f, dcy = d.y + dh * 0.5f;
            float gcx = g0 + gw * 0.5f,  gcy = g1 + gh * 0.5f;
            float e0 = (gcx - dcx) / (dw * 0.1f + 1e-8f);
            float e1 = (gcy - dcy) / (dh * 0.1f + 1e-8f);
            float e2 = logf(gw / (dw + 1e-8f) + 1e-8f) / 0.1f;
            float e3 = logf(gh / (dh + 1e-8f) + 1e-8f) / 0.1f;
            float4 lp = loc[(size_t)b * NP + p];
            float a, sl = 0.0f;
            a = fabsf(lp.x - e0); sl += (a < 1.0f) ? 0.5f * a * a : a - 0.5f;
            a = fabsf(lp.y - e1); sl += (a < 1.0f) ? 0.5f * a * a : a - 0.5f;
            a = fabsf(lp.z - e2); sl += (a < 1.0f) ? 0.5f * a * a : a - 0.5f;
            a = fabsf(lp.w - e3); sl += (a < 1.0f) ? 0.5f * a * a : a - 0.5f;
            locS += sl;

            float ccx = (g0 + g2) * 0.5f, ccy = (g1 + g3) * 0.5f;
            float ld = ccx - g0, rd = g2 - ccx, td = ccy - g1, bd = g3 - ccy;
            float centT = sqrtf((fminf(ld, rd) / fmaxf(ld, rd + 1e-8f)) *
                                (fminf(td, bd) / fmaxf(td, bd + 1e-8f)));
            float x = cent[(size_t)b * NP + p];
            float bce = fmaxf(x, 0.0f) - x * centT + log1pf(expf(-fabsf(x)));
            centS += bce;
            pfocS += focal;
            np++;
        }
    }

    // block reduce (shfl + tiny LDS)
    const int lane = t & 63, wv = t >> 6;
    float fnp = (float)np;
    #pragma unroll
    for (int off = 32; off > 0; off >>= 1) {
        locS  += __shfl_down(locS,  off);
        centS += __shfl_down(centS, off);
        pfocS += __shfl_down(pfocS, off);
        fnp   += __shfl_down(fnp,   off);
    }
    __shared__ float r0[4], r1[4], r2[4], r3[4];
    if (lane == 0) { r0[wv] = locS; r1[wv] = centS; r2[wv] = pfocS; r3[wv] = fnp; }
    __syncthreads();
    if (t == 0) {
        int idx = b * S_SPLIT + s;
        locP[idx]  = r0[0] + r0[1] + r0[2] + r0[3];
        centP[idx] = r1[0] + r1[1] + r1[2] + r1[3];
        pfocP[idx] = r2[0] + r2[1] + r2[2] + r2[3];
        nposP[idx] = (int)(r3[0] + r3[1] + r3[2] + r3[3]);
    }
}

// ---------------- Kernel 3: per-batch top-k (register-resident radix select) ----------------
__global__ __launch_bounds__(256) void k_topk(
    const float* __restrict__ lossc, const int* __restrict__ nposP,
    float* __restrict__ topkP, float* __restrict__ selcP)
{
    const int b = blockIdx.x, t = threadIdx.x;
    const int lane = t & 63, wv = t >> 6;
    __shared__ int s_c[4];
    __shared__ float s_f[4];

    unsigned ukey[NK];
    #pragma unroll
    for (int i = 0; i < NK; i++) {
        int p = i * 256 + t;
        ukey[i] = (p < NP) ? __float_as_uint(lossc[b * NP + p]) : 0u;
    }

    int np = 0;
    for (int s = 0; s < S_SPLIT; s++) np += nposP[b * S_SPLIT + s];
    const int k = min(3 * np, NP - 1);

    unsigned vk = 0;
    if (k > 0) {
        for (int bit = 30; bit >= 0; --bit) {
            unsigned trial = vk | (1u << bit);
            int cnt = 0;
            #pragma unroll
            for (int i = 0; i < NK; i++) cnt += (ukey[i] >= trial) ? 1 : 0;
            #pragma unroll
            for (int off = 32; off > 0; off >>= 1) cnt += __shfl_down(cnt, off);
            if (lane == 0) s_c[wv] = cnt;
            __syncthreads();
            int total = s_c[0] + s_c[1] + s_c[2] + s_c[3];
            __syncthreads();
            if (total >= k) vk = trial;
        }
    }

    int cgt = 0; float sgt = 0.0f;
    #pragma unroll
    for (int i = 0; i < NK; i++) {
        unsigned kk = ukey[i];
        if (kk > vk) { cgt++; sgt += __uint_as_float(kk); }
    }
    #pragma unroll
    for (int off = 32; off > 0; off >>= 1) {
        cgt += __shfl_down(cgt, off);
        sgt += __shfl_down(sgt, off);
    }
    if (lane == 0) { s_c[wv] = cgt; s_f[wv] = sgt; }
    __syncthreads();
    if (t == 0) {
        int   tc = s_c[0] + s_c[1] + s_c[2] + s_c[3];
        float ts = s_f[0] + s_f[1] + s_f[2] + s_f[3];
        float topk = (k > 0) ? (ts + (float)(k - tc) * __uint_as_float(vk)) : 0.0f;
        topkP[b] = topk;
        selcP[b] = (float)(np + k);
    }
}

// ---------------- Kernel 4: final combine (parallel partial + reduce) ----------------
__global__ __launch_bounds__(256) void k_final(
    const int* __restrict__ nposP, const float* __restrict__ locP,
    const float* __restrict__ centP, const float* __restrict__ pfocP,
    const float* __restrict__ topkP, const float* __restrict__ selcP,
    float* __restrict__ out)
{
    const int t = threadIdx.x;
    const int lane = t & 63, wv = t >> 6;
    float l = 0.0f, c = 0.0f, pf = 0.0f, np = 0.0f, tk = 0.0f, sc = 0.0f;
    for (int i = t; i < NB * S_SPLIT; i += 256) {
        np += (float)nposP[i]; l += locP[i]; c += centP[i]; pf += pfocP[i];
    }
    if (t < NB) { tk = topkP[t]; sc = selcP[t]; }

    #pragma unroll
    for (int off = 32; off > 0; off >>= 1) {
        l  += __shfl_down(l,  off);
        c  += __shfl_down(c,  off);
        pf += __shfl_down(pf, off);
        np += __shfl_down(np, off);
        tk += __shfl_down(tk, off);
        sc += __shfl_down(sc, off);
    }
    __shared__ float s6[6][4];
    if (lane == 0) {
        s6[0][wv] = l; s6[1][wv] = c; s6[2][wv] = pf;
        s6[3][wv] = np; s6[4][wv] = tk; s6[5][wv] = sc;
    }
    __syncthreads();
    if (t == 0) {
        float L  = s6[0][0] + s6[0][1] + s6[0][2] + s6[0][3];
        float C  = s6[1][0] + s6[1][1] + s6[1][2] + s6[1][3];
        float PF = s6[2][0] + s6[2][1] + s6[2][2] + s6[2][3];
        float NPs= s6[3][0] + s6[3][1] + s6[3][2] + s6[3][3];
        float TK = s6[4][0] + s6[4][1] + s6[4][2] + s6[4][3];
        float SC = s6[5][0] + s6[5][1] + s6[5][2] + s6[5][3];
        out[0] = 2.0f * (L / NPs) + (PF + TK) / SC + (C / NPs);
    }
}

extern "C" void kernel_launch(void* const* d_in, const int* in_sizes, int n_in,
                              void* d_out, int out_size, void* d_ws, size_t ws_size,
                              hipStream_t stream) {
    const float4* loc      = (const float4*)d_in[0];
    const float*  conf     = (const float*)d_in[1];
    const float*  cent     = (const float*)d_in[2];
    const float4* defaults = (const float4*)d_in[3];
    const float4* gtb      = (const float4*)d_in[4];
    const int*    gtl      = (const int*)d_in[5];
    float* out = (float*)d_out;

    const size_t BP = (size_t)NB * NP;
    char* w = (char*)d_ws;
    int*   bti   = (int*)w;                        // BP
    float* bto   = (float*)(w + BP * 4);           // BP
    float* lossc = (float*)(w + 2 * BP * 4);       // BP
    char* w2 = w + 3 * BP * 4;
    int*   nposP = (int*)w2;                                   // NB*S_SPLIT
    float* locP  = (float*)(w2 + 1 * NB * S_SPLIT * 4);
    float* centP = (float*)(w2 + 2 * NB * S_SPLIT * 4);
    float* pfocP = (float*)(w2 + 3 * NB * S_SPLIT * 4);
    float* topkP = (float*)(w2 + 4 * NB * S_SPLIT * 4);        // NB
    float* selcP = (float*)(w2 + 4 * NB * S_SPLIT * 4 + NB * 4);
    char* w3 = w2 + 4 * NB * S_SPLIT * 4 + 2 * NB * 4;
    float* pbv = (float*)w3;                                   // NB*PSPLIT*NM
    int*   pbi = (int*)(w3 + NB * PSPLIT * NM * 4);

    k_match_part<<<dim3(NB, PSPLIT), 256, 0, stream>>>(defaults, gtb, bti, bto, pbv, pbi);
    k_match_fix<<<NB, 64, 0, stream>>>(pbv, pbi, bti, bto);
    k_loss<<<dim3(NB, S_SPLIT), 256, 0, stream>>>(loc, conf, cent, defaults, gtb, gtl,
                                                  bti, bto, lossc, nposP, locP, centP, pfocP);
    k_topk<<<NB, 256, 0, stream>>>(lossc, nposP, topkP, selcP);
    k_final<<<1, 256, 0, stream>>>(nposP, locP, centP, pfocP, topkP, selcP, out);
}